// Round 3
// baseline (476.478 us; speedup 1.0000x reference)
//
#include <hip/hip_runtime.h>

typedef unsigned short u16;
typedef u16 u16x8 __attribute__((ext_vector_type(8)));
typedef __bf16 bf16x8 __attribute__((ext_vector_type(8)));
typedef float f32x4 __attribute__((ext_vector_type(4)));

#define NPIX 100352           // 32*56*56
#define KTOT 2304             // 3*3*256
#define IMG_PAD (58 * 58 * 256)

static __device__ __forceinline__ u16 f2bf(float f) {
  unsigned u = __float_as_uint(f);
  return (u16)((u + 0x7fffu + ((u >> 16) & 1u)) >> 16);
}

static __device__ __forceinline__ void gld_lds16(const u16* g, u16* l) {
  __builtin_amdgcn_global_load_lds(
      (const __attribute__((address_space(1))) void*)g,
      (__attribute__((address_space(3))) void*)l, 16, 0, 0);
}

// ---------- scale[f] = sum_k |w[k][f]| ----------
__global__ void scale_accum_k(const float* __restrict__ w, float* __restrict__ scale) {
  const int t = threadIdx.x;
  const float* p = w + (long)blockIdx.x * 64 * 256 + t;
  float acc = 0.f;
#pragma unroll
  for (int e = 0; e < 64; ++e) acc += fabsf(p[(long)e * 256]);
  atomicAdd(&scale[t], acc);
}

// ---------- wp[f][k] = bf16( scale[f]/2304 * sign(w[k][f]) * mask[k][f] ) ----------
__global__ void pack_w_k(const float* __restrict__ w, const float* __restrict__ mask,
                         const float* __restrict__ ssum, u16* __restrict__ wp) {
  __shared__ u16 t[128][33];
  const int k0 = blockIdx.x * 32;
  const int f0 = blockIdx.y * 128;
  const int tid = threadIdx.x;
#pragma unroll
  for (int i = 0; i < 16; ++i) {
    int idx = tid + i * 256;
    int kk = idx >> 7;
    int ff = idx & 127;
    long g = (long)(k0 + kk) * 256 + f0 + ff;
    float wv = w[g];
    float mv = mask[g];
    float sc = ssum[f0 + ff] * (1.0f / 2304.0f);
    float sg = (wv > 0.f) ? 1.f : ((wv < 0.f) ? -1.f : 0.f);
    t[ff][kk] = f2bf(sc * sg * mv);
  }
  __syncthreads();
#pragma unroll
  for (int i = 0; i < 8; ++i) {
    int idx = tid + i * 256;
    int row = idx >> 4;
    int c = idx & 15;
    unsigned v = (unsigned)t[row][2 * c] | ((unsigned)t[row][2 * c + 1] << 16);
    *(unsigned*)(wp + (long)(f0 + row) * KTOT + k0 + 2 * c) = v;
  }
}

// ---------- x fp32 -> bf16 padded [32][58][58][256], zero border written here ----------
__global__ void fill_xpad2_k(const float* __restrict__ x, u16* __restrict__ xp) {
  const long idx = (long)blockIdx.x * 256 + threadIdx.x;   // one u16x8 chunk
  const int c = (int)(idx & 31);
  const long p = idx >> 5;                // img*3364 + ph*58 + pw
  const int img = (int)(p / 3364);
  const int r = (int)(p % 3364);
  const int ph = r / 58, pw = r % 58;
  u16x8 v = {0, 0, 0, 0, 0, 0, 0, 0};
  if (ph >= 1 && ph <= 56 && pw >= 1 && pw <= 56) {
    const float* s = x + ((long)img * 3136 + (ph - 1) * 56 + (pw - 1)) * 256 + c * 8;
    float4 a = *(const float4*)s;
    float4 b = *(const float4*)(s + 4);
    v[0] = f2bf(a.x); v[1] = f2bf(a.y); v[2] = f2bf(a.z); v[3] = f2bf(a.w);
    v[4] = f2bf(b.x); v[5] = f2bf(b.y); v[6] = f2bf(b.z); v[7] = f2bf(b.w);
  }
  *(u16x8*)(xp + idx * 8) = v;
}

// ---------- implicit-GEMM conv, barrier-light: A direct global, B LDS per khw-half ----
// C[M=100352,N=256] = A[M,K=2304]*B^T; 128x128 tile, 4 waves, 4x4 MFMA 16x16x32 bf16.
__global__ __launch_bounds__(256) void conv_gemm3_k(
    const u16* __restrict__ xpad, const u16* __restrict__ wp, float* __restrict__ out) {
  __shared__ u16 Bs[128 * 128];   // 32 KB: row r (256B) holds 16 chunks, pc = lc ^ (r&7)

  const int tid = threadIdx.x;
  const int lane = tid & 63;
  const int wv = tid >> 6;
  const int m0 = blockIdx.x * 128;
  const int n0 = blockIdx.y * 128;

  // --- B staging map: instr i stages rows [i*16, i*16+16); thread t -> row i*16+(t>>4),
  //     physical chunk t&15, fetching logical chunk (t&15) ^ ((t>>4)&7).
  const int srow = tid >> 4;                       // 0..15
  const int slc = (tid & 15) ^ (srow & 7);         // logical chunk fetched
  const u16* bstage = wp + (long)(n0 + srow) * KTOT + slc * 8;
  u16* blds = Bs + wv * 512;                       // + i*2048 per instr (wave-uniform)

  // --- MFMA lane mapping
  const int lm = lane & 15, kq = lane >> 4;
  const int wm = wv & 1, wn = wv >> 1;

  // A direct-load row bases (include kq*8 k-offset)
  const u16* abase[4];
#pragma unroll
  for (int mi = 0; mi < 4; ++mi) {
    const int m = m0 + wm * 64 + mi * 16 + lm;
    const int img = m / 3136, q = m % 3136;
    abase[mi] = xpad + (long)img * IMG_PAD + ((q / 56 + 1) * 58 + (q % 56) + 1) * 256 + kq * 8;
  }

  // B frag read: row = wn*64+ni*16+lm (128 u16 per row), phys chunk = (ctl*4+kq)^(lm&7)
  int bboff[4];
#pragma unroll
  for (int ni = 0; ni < 4; ++ni) bboff[ni] = (wn * 64 + ni * 16 + lm) * 128;
  int px[4];
#pragma unroll
  for (int ctl = 0; ctl < 4; ++ctl) px[ctl] = ((ctl * 4 + kq) ^ (lm & 7)) * 8;

  f32x4 acc[4][4] = {};

  for (int khw = 0; khw < 9; ++khw) {
    const int d = ((khw / 3 - 1) * 58 + (khw % 3 - 1)) * 256;
#pragma unroll
    for (int half = 0; half < 2; ++half) {
      __syncthreads();   // previous half's B reads complete before overwrite
      const u16* bg = bstage + khw * 256 + half * 128;
#pragma unroll
      for (int i = 0; i < 8; ++i)
        gld_lds16(bg + (long)i * 16 * KTOT, blds + i * 2048);
      __syncthreads();   // staging visible (drains DMA)

#pragma unroll
      for (int ctl = 0; ctl < 4; ++ctl) {
        const int koff = d + (half * 4 + ctl) * 32;   // u16 offset into A row
        bf16x8 av[4], bv[4];
#pragma unroll
        for (int mi = 0; mi < 4; ++mi) av[mi] = *(const bf16x8*)(abase[mi] + koff);
#pragma unroll
        for (int ni = 0; ni < 4; ++ni) bv[ni] = *(const bf16x8*)(Bs + bboff[ni] + px[ctl]);
#pragma unroll
        for (int mi = 0; mi < 4; ++mi)
#pragma unroll
          for (int ni = 0; ni < 4; ++ni)
            acc[mi][ni] = __builtin_amdgcn_mfma_f32_16x16x32_bf16(av[mi], bv[ni], acc[mi][ni], 0, 0, 0);
      }
    }
  }

  // D: col = lane&15 (n), row = quad*4 + reg (m)
  float* op = out + (long)(m0 + wm * 64 + kq * 4) * 256 + n0 + wn * 64 + lm;
#pragma unroll
  for (int mi = 0; mi < 4; ++mi) {
#pragma unroll
    for (int ni = 0; ni < 4; ++ni) {
      float* p = op + (long)mi * 16 * 256 + ni * 16;
      f32x4 v = acc[mi][ni];
      p[0] = v[0];
      p[256] = v[1];
      p[512] = v[2];
      p[768] = v[3];
    }
  }
}

// ---------- fallback (round-1 verified path) if ws too small for xpad ----------
__global__ __launch_bounds__(256) void conv_gemm_fb_k(
    const float* __restrict__ x, const u16* __restrict__ wp, float* __restrict__ out) {
  __shared__ u16 As[128 * 40];
  __shared__ u16 Bs[128 * 40];
  const int tid = threadIdx.x;
  const int m0 = blockIdx.x * 128;
  const int n0 = blockIdx.y * 128;
  const int cc = tid & 3;
  const int r0 = tid >> 2;
  const int gm0 = m0 + r0;
  const int gm1 = gm0 + 64;
  const int pix0 = gm0 % 3136, oh0 = pix0 / 56, ow0 = pix0 % 56;
  const int pix1 = gm1 % 3136, oh1 = pix1 / 56, ow1 = pix1 % 56;
  const int lane = tid & 63;
  const int wv = tid >> 6;
  const int wm = wv & 1, wn = wv >> 1;
  const int lm = lane & 15, kq = lane >> 4;
  const int aoff = (wm * 64 + lm) * 40 + kq * 8;
  const int boff = (wn * 64 + lm) * 40 + kq * 8;
  u16* as0 = As + r0 * 40 + cc * 8;
  u16* as1 = As + (r0 + 64) * 40 + cc * 8;
  u16* bs0 = Bs + r0 * 40 + cc * 8;
  u16* bs1 = Bs + (r0 + 64) * 40 + cc * 8;
  const u16* wr0 = wp + (long)(n0 + r0) * KTOT + cc * 8;
  const u16* wr1 = wr0 + (long)64 * KTOT;
  f32x4 acc[4][4] = {};
  for (int khw = 0; khw < 9; ++khw) {
    const int dh = khw / 3 - 1;
    const int dw = khw % 3 - 1;
    const bool v0 = ((unsigned)(oh0 + dh) < 56u) && ((unsigned)(ow0 + dw) < 56u);
    const bool v1 = ((unsigned)(oh1 + dh) < 56u) && ((unsigned)(ow1 + dw) < 56u);
    const long p0 = ((long)gm0 + dh * 56 + dw) * 256 + cc * 8;
    const long p1 = ((long)gm1 + dh * 56 + dw) * 256 + cc * 8;
    const u16* wk0 = wr0 + khw * 256;
    const u16* wk1 = wr1 + khw * 256;
    for (int ct = 0; ct < 8; ++ct) {
      const int ci0 = ct * 32;
      u16x8 a0 = {0,0,0,0,0,0,0,0}, a1 = {0,0,0,0,0,0,0,0};
      float4 l0 = make_float4(0,0,0,0), h0 = make_float4(0,0,0,0);
      float4 l1 = make_float4(0,0,0,0), h1 = make_float4(0,0,0,0);
      if (v0) { l0 = *(const float4*)(x + p0 + ci0); h0 = *(const float4*)(x + p0 + ci0 + 4); }
      if (v1) { l1 = *(const float4*)(x + p1 + ci0); h1 = *(const float4*)(x + p1 + ci0 + 4); }
      a0[0]=f2bf(l0.x); a0[1]=f2bf(l0.y); a0[2]=f2bf(l0.z); a0[3]=f2bf(l0.w);
      a0[4]=f2bf(h0.x); a0[5]=f2bf(h0.y); a0[6]=f2bf(h0.z); a0[7]=f2bf(h0.w);
      a1[0]=f2bf(l1.x); a1[1]=f2bf(l1.y); a1[2]=f2bf(l1.z); a1[3]=f2bf(l1.w);
      a1[4]=f2bf(h1.x); a1[5]=f2bf(h1.y); a1[6]=f2bf(h1.z); a1[7]=f2bf(h1.w);
      u16x8 b0 = *(const u16x8*)(wk0 + ci0);
      u16x8 b1 = *(const u16x8*)(wk1 + ci0);
      __syncthreads();
      *(u16x8*)as0 = a0; *(u16x8*)as1 = a1;
      *(u16x8*)bs0 = b0; *(u16x8*)bs1 = b1;
      __syncthreads();
      bf16x8 av[4], bv[4];
#pragma unroll
      for (int i = 0; i < 4; ++i) av[i] = *(const bf16x8*)(As + aoff + i * 640);
#pragma unroll
      for (int i = 0; i < 4; ++i) bv[i] = *(const bf16x8*)(Bs + boff + i * 640);
#pragma unroll
      for (int mi = 0; mi < 4; ++mi)
#pragma unroll
        for (int ni = 0; ni < 4; ++ni)
          acc[mi][ni] = __builtin_amdgcn_mfma_f32_16x16x32_bf16(av[mi], bv[ni], acc[mi][ni], 0, 0, 0);
    }
  }
  float* op = out + (long)(m0 + wm * 64 + kq * 4) * 256 + n0 + wn * 64 + lm;
#pragma unroll
  for (int mi = 0; mi < 4; ++mi)
#pragma unroll
    for (int ni = 0; ni < 4; ++ni) {
      float* p = op + (long)mi * 16 * 256 + ni * 16;
      f32x4 v = acc[mi][ni];
      p[0] = v[0]; p[256] = v[1]; p[512] = v[2]; p[768] = v[3];
    }
}

extern "C" void kernel_launch(void* const* d_in, const int* in_sizes, int n_in,
                              void* d_out, int out_size, void* d_ws, size_t ws_size,
                              hipStream_t stream) {
  const float* x = (const float*)d_in[0];
  const float* w = (const float*)d_in[1];
  const float* mask = (const float*)d_in[2];
  float* out = (float*)d_out;

  float* scale = (float*)d_ws;                       // 1024 B + pad
  u16* wp = (u16*)((char*)d_ws + 1088);              // 1,179,648 B  [f][k] bf16
  u16* xpad = (u16*)((char*)d_ws + 1088 + 1179648);  // 55,115,776 B padded bf16 x
  const size_t xpad_bytes = (size_t)32 * IMG_PAD * 2;
  const size_t need = 1088 + 1179648 + xpad_bytes;

  hipMemsetAsync(d_ws, 0, 1088, stream);
  scale_accum_k<<<36, 256, 0, stream>>>(w, scale);
  pack_w_k<<<dim3(72, 2), 256, 0, stream>>>(w, mask, scale, wp);
  if (ws_size >= need) {
    fill_xpad2_k<<<(32 * 3364 * 32) / 256, 256, 0, stream>>>(x, xpad);
    conv_gemm3_k<<<dim3(784, 2), 256, 0, stream>>>(xpad, wp, out);
  } else {
    conv_gemm_fb_k<<<dim3(784, 2), 256, 0, stream>>>(x, wp, out);
  }
}

// Round 4
// 377.911 us; speedup vs baseline: 1.2608x; 1.2608x over previous
//
#include <hip/hip_runtime.h>

typedef unsigned short u16;
typedef u16 u16x8 __attribute__((ext_vector_type(8)));
typedef __bf16 bf16x8 __attribute__((ext_vector_type(8)));
typedef float f32x4 __attribute__((ext_vector_type(4)));

#define NPIX 100352           // 32*56*56
#define KTOT 2304             // 3*3*256
#define IMG_PAD (58 * 58 * 256)

static __device__ __forceinline__ u16 f2bf(float f) {
  unsigned u = __float_as_uint(f);
  return (u16)((u + 0x7fffu + ((u >> 16) & 1u)) >> 16);
}

static __device__ __forceinline__ void gld_lds16(const u16* g, u16* l) {
  __builtin_amdgcn_global_load_lds(
      (const __attribute__((address_space(1))) void*)g,
      (__attribute__((address_space(3))) void*)l, 16, 0, 0);
}

// ---------- scale[f] = sum_k |w[k][f]| ----------
__global__ void scale_accum_k(const float* __restrict__ w, float* __restrict__ scale) {
  const int t = threadIdx.x;
  const float* p = w + (long)blockIdx.x * 64 * 256 + t;
  float acc = 0.f;
#pragma unroll
  for (int e = 0; e < 64; ++e) acc += fabsf(p[(long)e * 256]);
  atomicAdd(&scale[t], acc);
}

// ---------- wp[f][k] = bf16( scale[f]/2304 * sign(w[k][f]) * mask[k][f] ) ----------
__global__ void pack_w_k(const float* __restrict__ w, const float* __restrict__ mask,
                         const float* __restrict__ ssum, u16* __restrict__ wp) {
  __shared__ u16 t[128][33];
  const int k0 = blockIdx.x * 32;
  const int f0 = blockIdx.y * 128;
  const int tid = threadIdx.x;
#pragma unroll
  for (int i = 0; i < 16; ++i) {
    int idx = tid + i * 256;
    int kk = idx >> 7;
    int ff = idx & 127;
    long g = (long)(k0 + kk) * 256 + f0 + ff;
    float wv = w[g];
    float mv = mask[g];
    float sc = ssum[f0 + ff] * (1.0f / 2304.0f);
    float sg = (wv > 0.f) ? 1.f : ((wv < 0.f) ? -1.f : 0.f);
    t[ff][kk] = f2bf(sc * sg * mv);
  }
  __syncthreads();
#pragma unroll
  for (int i = 0; i < 8; ++i) {
    int idx = tid + i * 256;
    int row = idx >> 4;
    int c = idx & 15;
    unsigned v = (unsigned)t[row][2 * c] | ((unsigned)t[row][2 * c + 1] << 16);
    *(unsigned*)(wp + (long)(f0 + row) * KTOT + k0 + 2 * c) = v;
  }
}

// ---------- x fp32 -> bf16 padded [32][58][58][256], zero border written here ----------
__global__ void fill_xpad2_k(const float* __restrict__ x, u16* __restrict__ xp) {
  const long idx = (long)blockIdx.x * 256 + threadIdx.x;   // one u16x8 chunk
  const int c = (int)(idx & 31);
  const long p = idx >> 5;                // img*3364 + ph*58 + pw
  const int img = (int)(p / 3364);
  const int r = (int)(p % 3364);
  const int ph = r / 58, pw = r % 58;
  u16x8 v = {0, 0, 0, 0, 0, 0, 0, 0};
  if (ph >= 1 && ph <= 56 && pw >= 1 && pw <= 56) {
    const float* s = x + ((long)img * 3136 + (ph - 1) * 56 + (pw - 1)) * 256 + c * 8;
    float4 a = *(const float4*)s;
    float4 b = *(const float4*)(s + 4);
    v[0] = f2bf(a.x); v[1] = f2bf(a.y); v[2] = f2bf(a.z); v[3] = f2bf(a.w);
    v[4] = f2bf(b.x); v[5] = f2bf(b.y); v[6] = f2bf(b.z); v[7] = f2bf(b.w);
  }
  *(u16x8*)(xp + idx * 8) = v;
}

// ---------- implicit-GEMM conv: m97 DMA structure, BK=64 (36 barrier-pairs) ----------
// C[M=100352,N=256] = A[M,K=2304]*B^T; 128x128 tile, 4 waves, 4x4 MFMA 16x16x32 bf16.
// LDS rows: 64 u16 = 128 B = 8 chunks of 16 B; chunk swizzle pc = lc ^ (row&7).
__global__ __launch_bounds__(256) void conv_gemm4_k(
    const u16* __restrict__ xpad, const u16* __restrict__ wp, float* __restrict__ out) {
  __shared__ u16 As[128 * 64];   // 16 KB
  __shared__ u16 Bs[128 * 64];   // 16 KB

  const int tid = threadIdx.x;
  const int lane = tid & 63;
  const int wv = tid >> 6;
  const int m0 = blockIdx.x * 128;
  const int n0 = blockIdx.y * 128;

  // --- staging map: DMA instr i (i=0..3), wave wv covers rows [(i*4+wv)*8, +8)
  //     lane l -> row sub = l>>3, physical chunk = l&7, logical chunk fetched:
  const int lsub = lane >> 3;                       // 0..7
  const int lc = (lane & 7) ^ (lsub & 7);           // swizzle
  const u16* aptr[4];
  const u16* bptr[4];
#pragma unroll
  for (int i = 0; i < 4; ++i) {
    const int row = (i * 4 + wv) * 8 + lsub;        // 0..127, each exactly once
    const int m = m0 + row;
    const int img = m / 3136, q = m % 3136;
    aptr[i] = xpad + (long)img * IMG_PAD + ((q / 56 + 1) * 58 + (q % 56) + 1) * 256 + lc * 8;
    bptr[i] = wp + (long)(n0 + row) * KTOT + lc * 8;
  }
  // wave-uniform LDS DMA bases (u16 units): instr i -> (i*4+wv)*512
  const int ldsb = wv * 512;

  // --- MFMA lane mapping
  const int lm = lane & 15, kq = lane >> 4;
  const int wm = wv & 1, wn = wv >> 1;
  // frag read offsets: row = (wm*64 + mi*16 + lm), pc = (ct*4+kq) ^ (lm&7)
  int aoff[2], boff[2];
#pragma unroll
  for (int ct = 0; ct < 2; ++ct) {
    const int pc = ((ct * 4 + kq) ^ (lm & 7)) * 8;
    aoff[ct] = (wm * 64 + lm) * 64 + pc;
    boff[ct] = (wn * 64 + lm) * 64 + pc;
  }

  f32x4 acc[4][4] = {};

  for (int khw = 0; khw < 9; ++khw) {
    const int d = ((khw / 3 - 1) * 58 + (khw % 3 - 1)) * 256;   // halo offset (u16)
    const int bk = khw * 256;
#pragma unroll
    for (int j = 0; j < 4; ++j) {                    // 4 x BK=64 per khw
      const int ka = d + j * 64;
      const int kb = bk + j * 64;
      __syncthreads();   // prev pair's frag reads done before DMA overwrites
#pragma unroll
      for (int i = 0; i < 4; ++i) {
        gld_lds16(aptr[i] + ka, As + i * 2048 + ldsb);
        gld_lds16(bptr[i] + kb, Bs + i * 2048 + ldsb);
      }
      __syncthreads();   // DMA visible
#pragma unroll
      for (int ct = 0; ct < 2; ++ct) {
        bf16x8 av[4], bv[4];
#pragma unroll
        for (int mi = 0; mi < 4; ++mi) av[mi] = *(const bf16x8*)(As + aoff[ct] + mi * 1024);
#pragma unroll
        for (int ni = 0; ni < 4; ++ni) bv[ni] = *(const bf16x8*)(Bs + boff[ct] + ni * 1024);
#pragma unroll
        for (int mi = 0; mi < 4; ++mi)
#pragma unroll
          for (int ni = 0; ni < 4; ++ni)
            acc[mi][ni] = __builtin_amdgcn_mfma_f32_16x16x32_bf16(av[mi], bv[ni], acc[mi][ni], 0, 0, 0);
      }
    }
  }

  // D: col = lane&15 (n), row = quad*4 + reg (m)
  float* op = out + (long)(m0 + wm * 64 + kq * 4) * 256 + n0 + wn * 64 + lm;
#pragma unroll
  for (int mi = 0; mi < 4; ++mi) {
#pragma unroll
    for (int ni = 0; ni < 4; ++ni) {
      float* p = op + (long)mi * 16 * 256 + ni * 16;
      f32x4 v = acc[mi][ni];
      p[0] = v[0];
      p[256] = v[1];
      p[512] = v[2];
      p[768] = v[3];
    }
  }
}

// ---------- fallback (round-1 verified path) if ws too small for xpad ----------
__global__ __launch_bounds__(256) void conv_gemm_fb_k(
    const float* __restrict__ x, const u16* __restrict__ wp, float* __restrict__ out) {
  __shared__ u16 As[128 * 40];
  __shared__ u16 Bs[128 * 40];
  const int tid = threadIdx.x;
  const int m0 = blockIdx.x * 128;
  const int n0 = blockIdx.y * 128;
  const int cc = tid & 3;
  const int r0 = tid >> 2;
  const int gm0 = m0 + r0;
  const int gm1 = gm0 + 64;
  const int pix0 = gm0 % 3136, oh0 = pix0 / 56, ow0 = pix0 % 56;
  const int pix1 = gm1 % 3136, oh1 = pix1 / 56, ow1 = pix1 % 56;
  const int lane = tid & 63;
  const int wv = tid >> 6;
  const int wm = wv & 1, wn = wv >> 1;
  const int lm = lane & 15, kq = lane >> 4;
  const int aoff = (wm * 64 + lm) * 40 + kq * 8;
  const int boff = (wn * 64 + lm) * 40 + kq * 8;
  u16* as0 = As + r0 * 40 + cc * 8;
  u16* as1 = As + (r0 + 64) * 40 + cc * 8;
  u16* bs0 = Bs + r0 * 40 + cc * 8;
  u16* bs1 = Bs + (r0 + 64) * 40 + cc * 8;
  const u16* wr0 = wp + (long)(n0 + r0) * KTOT + cc * 8;
  const u16* wr1 = wr0 + (long)64 * KTOT;
  f32x4 acc[4][4] = {};
  for (int khw = 0; khw < 9; ++khw) {
    const int dh = khw / 3 - 1;
    const int dw = khw % 3 - 1;
    const bool v0 = ((unsigned)(oh0 + dh) < 56u) && ((unsigned)(ow0 + dw) < 56u);
    const bool v1 = ((unsigned)(oh1 + dh) < 56u) && ((unsigned)(ow1 + dw) < 56u);
    const long p0 = ((long)gm0 + dh * 56 + dw) * 256 + cc * 8;
    const long p1 = ((long)gm1 + dh * 56 + dw) * 256 + cc * 8;
    const u16* wk0 = wr0 + khw * 256;
    const u16* wk1 = wr1 + khw * 256;
    for (int ct = 0; ct < 8; ++ct) {
      const int ci0 = ct * 32;
      u16x8 a0 = {0,0,0,0,0,0,0,0}, a1 = {0,0,0,0,0,0,0,0};
      float4 l0 = make_float4(0,0,0,0), h0 = make_float4(0,0,0,0);
      float4 l1 = make_float4(0,0,0,0), h1 = make_float4(0,0,0,0);
      if (v0) { l0 = *(const float4*)(x + p0 + ci0); h0 = *(const float4*)(x + p0 + ci0 + 4); }
      if (v1) { l1 = *(const float4*)(x + p1 + ci0); h1 = *(const float4*)(x + p1 + ci0 + 4); }
      a0[0]=f2bf(l0.x); a0[1]=f2bf(l0.y); a0[2]=f2bf(l0.z); a0[3]=f2bf(l0.w);
      a0[4]=f2bf(h0.x); a0[5]=f2bf(h0.y); a0[6]=f2bf(h0.z); a0[7]=f2bf(h0.w);
      a1[0]=f2bf(l1.x); a1[1]=f2bf(l1.y); a1[2]=f2bf(l1.z); a1[3]=f2bf(l1.w);
      a1[4]=f2bf(h1.x); a1[5]=f2bf(h1.y); a1[6]=f2bf(h1.z); a1[7]=f2bf(h1.w);
      u16x8 b0 = *(const u16x8*)(wk0 + ci0);
      u16x8 b1 = *(const u16x8*)(wk1 + ci0);
      __syncthreads();
      *(u16x8*)as0 = a0; *(u16x8*)as1 = a1;
      *(u16x8*)bs0 = b0; *(u16x8*)bs1 = b1;
      __syncthreads();
      bf16x8 av[4], bv[4];
#pragma unroll
      for (int i = 0; i < 4; ++i) av[i] = *(const bf16x8*)(As + aoff + i * 640);
#pragma unroll
      for (int i = 0; i < 4; ++i) bv[i] = *(const bf16x8*)(Bs + boff + i * 640);
#pragma unroll
      for (int mi = 0; mi < 4; ++mi)
#pragma unroll
        for (int ni = 0; ni < 4; ++ni)
          acc[mi][ni] = __builtin_amdgcn_mfma_f32_16x16x32_bf16(av[mi], bv[ni], acc[mi][ni], 0, 0, 0);
    }
  }
  float* op = out + (long)(m0 + wm * 64 + kq * 4) * 256 + n0 + wn * 64 + lm;
#pragma unroll
  for (int mi = 0; mi < 4; ++mi)
#pragma unroll
    for (int ni = 0; ni < 4; ++ni) {
      float* p = op + (long)mi * 16 * 256 + ni * 16;
      f32x4 v = acc[mi][ni];
      p[0] = v[0]; p[256] = v[1]; p[512] = v[2]; p[768] = v[3];
    }
}

extern "C" void kernel_launch(void* const* d_in, const int* in_sizes, int n_in,
                              void* d_out, int out_size, void* d_ws, size_t ws_size,
                              hipStream_t stream) {
  const float* x = (const float*)d_in[0];
  const float* w = (const float*)d_in[1];
  const float* mask = (const float*)d_in[2];
  float* out = (float*)d_out;

  float* scale = (float*)d_ws;                       // 1024 B + pad
  u16* wp = (u16*)((char*)d_ws + 1088);              // 1,179,648 B  [f][k] bf16
  u16* xpad = (u16*)((char*)d_ws + 1088 + 1179648);  // 55,115,776 B padded bf16 x
  const size_t xpad_bytes = (size_t)32 * IMG_PAD * 2;
  const size_t need = 1088 + 1179648 + xpad_bytes;

  hipMemsetAsync(d_ws, 0, 1088, stream);
  scale_accum_k<<<36, 256, 0, stream>>>(w, scale);
  pack_w_k<<<dim3(72, 2), 256, 0, stream>>>(w, mask, scale, wp);
  if (ws_size >= need) {
    fill_xpad2_k<<<(32 * 3364 * 32) / 256, 256, 0, stream>>>(x, xpad);
    conv_gemm4_k<<<dim3(784, 2), 256, 0, stream>>>(xpad, wp, out);
  } else {
    conv_gemm_fb_k<<<dim3(784, 2), 256, 0, stream>>>(x, wp, out);
  }
}